// Round 3
// baseline (1407.198 us; speedup 1.0000x reference)
//
#include <hip/hip_runtime.h>
#include <hip/hip_bf16.h>

typedef __attribute__((ext_vector_type(4))) float f32x4;
typedef __attribute__((ext_vector_type(8))) short short8;
typedef __attribute__((ext_vector_type(4))) int i32x4;
typedef __attribute__((ext_vector_type(2))) unsigned int u32x2;
typedef __attribute__((ext_vector_type(4))) unsigned short u16x4;

static __device__ __forceinline__ unsigned short f2bf(float f) {
  unsigned u = __builtin_bit_cast(unsigned, f);
  u = u + 0x7FFFu + ((u >> 16) & 1u);   // RNE
  return (unsigned short)(u >> 16);
}
static __device__ __forceinline__ float bf2f(unsigned short b) {
  unsigned u = ((unsigned)b) << 16;
  return __builtin_bit_cast(float, u);
}
static __device__ __forceinline__ float sigmoidf_fast(float x) {
  return __builtin_amdgcn_rcpf(1.f + __expf(-x));
}
static __device__ __forceinline__ float tanhf_fast(float x) {
  x = fminf(20.f, fmaxf(-20.f, x));
  float e = __expf(2.f * x);
  return (e - 1.f) * __builtin_amdgcn_rcpf(e + 1.f);
}

// ---------------- cast f32 -> bf16 (x4 vectorized) ----------------
__global__ void cast_bf16_kernel(const float* __restrict__ in,
                                 unsigned short* __restrict__ out, int n4) {
  int i = blockIdx.x * blockDim.x + threadIdx.x;
  if (i >= n4) return;
  f32x4 v = ((const f32x4*)in)[i];
  u16x4 o;
  o[0] = f2bf(v[0]); o[1] = f2bf(v[1]); o[2] = f2bf(v[2]); o[3] = f2bf(v[3]);
  ((u16x4*)out)[i] = o;
}

// ---------------- cast f32 -> hi/lo bf16 pair ----------------
__global__ void cast_split_kernel(const float* __restrict__ in,
                                  unsigned short* __restrict__ oh,
                                  unsigned short* __restrict__ ol, int n4) {
  int i = blockIdx.x * blockDim.x + threadIdx.x;
  if (i >= n4) return;
  f32x4 v = ((const f32x4*)in)[i];
  u16x4 h, l;
#pragma unroll
  for (int j = 0; j < 4; ++j) {
    unsigned short hb = f2bf(v[j]);
    h[j] = hb;
    l[j] = f2bf(v[j] - bf2f(hb));
  }
  ((u16x4*)oh)[i] = h;
  ((u16x4*)ol)[i] = l;
}

// ---------------- transpose + cast: (R,C) f32 -> (C,R) bf16 ----------------
__global__ void tcast_kernel(const float* __restrict__ in,
                             unsigned short* __restrict__ out, int R, int C) {
  int i = blockIdx.x * blockDim.x + threadIdx.x;
  if (i >= R * C) return;
  int r = i / C, c = i % C;
  out[(size_t)c * R + r] = f2bf(in[i]);
}

// ---------------- transpose + split cast: (R,C) f32 -> (C,R) hi/lo bf16 ----------------
__global__ void tcast_split_kernel(const float* __restrict__ in,
                                   unsigned short* __restrict__ oh,
                                   unsigned short* __restrict__ ol, int R, int C) {
  int i = blockIdx.x * blockDim.x + threadIdx.x;
  if (i >= R * C) return;
  int r = i / C, c = i % C;
  float v = in[i];
  unsigned short hb = f2bf(v);
  oh[(size_t)c * R + r] = hb;
  ol[(size_t)c * R + r] = f2bf(v - bf2f(hb));
}

// ---------------- f gate: one wave per token row (pure f32) ----------------
__global__ __launch_bounds__(256) void fgate_kernel(const float* __restrict__ x,
                                                    const float* __restrict__ Wf,
                                                    const float* __restrict__ bfv,
                                                    float* __restrict__ fbuf) {
  int wid = (blockIdx.x * blockDim.x + threadIdx.x) >> 6;  // token row 0..4095
  int lane = threadIdx.x & 63;
  const float* xr = x + (size_t)wid * 1024;
  float acc[8] = {0.f, 0.f, 0.f, 0.f, 0.f, 0.f, 0.f, 0.f};
#pragma unroll 4
  for (int it = 0; it < 16; ++it) {
    int d = it * 64 + lane;
    float xv = xr[d];
    f32x4 w0 = *(const f32x4*)(Wf + (size_t)d * 8);
    f32x4 w1 = *(const f32x4*)(Wf + (size_t)d * 8 + 4);
    acc[0] += xv * w0[0]; acc[1] += xv * w0[1];
    acc[2] += xv * w0[2]; acc[3] += xv * w0[3];
    acc[4] += xv * w1[0]; acc[5] += xv * w1[1];
    acc[6] += xv * w1[2]; acc[7] += xv * w1[3];
  }
#pragma unroll
  for (int n = 0; n < 8; ++n) {
#pragma unroll
    for (int m = 1; m < 64; m <<= 1) acc[n] += __shfl_xor(acc[n], m, 64);
  }
  if (lane == 0) {
#pragma unroll
    for (int n = 0; n < 8; ++n)
      fbuf[(size_t)wid * 8 + n] = sigmoidf_fast(acc[n] + bfv[n]);
  }
}

// ---------------- causal depthwise conv (KC=4) + SiLU (pure f32) ----------------
__global__ void conv_silu_kernel(const float* __restrict__ pre,
                                 const float* __restrict__ cw,
                                 float* __restrict__ outb) {
  int i = blockIdx.x * blockDim.x + threadIdx.x;  // B*L*512
  int c = i & 511;
  int l = (i >> 9) & 1023;
  float w0 = cw[c * 4 + 0], w1 = cw[c * 4 + 1], w2 = cw[c * 4 + 2], w3 = cw[c * 4 + 3];
  const float* p = pre + (size_t)i;
  float acc = w3 * p[0];
  if (l >= 1) acc += w2 * p[-512];
  if (l >= 2) acc += w1 * p[-1024];
  if (l >= 3) acc += w0 * p[-1536];
  outb[i] = acc * sigmoidf_fast(acc);
}

// ---------------- plain bf16 MFMA GEMM: C(M,Nd) = A * Bt^T ----------------
__global__ __launch_bounds__(256) void gemm_bf16_kernel(
    const unsigned short* __restrict__ A, const unsigned short* __restrict__ Bt,
    float* __restrict__ C, int Kd, int Nd, size_t BtStride, size_t CStride) {
  __shared__ unsigned short Ash[128][40];
  __shared__ unsigned short Bsh[128][40];
  const int tid = threadIdx.x;
  const int wave = tid >> 6, lane = tid & 63;
  const int g = lane >> 4, lr = lane & 15;
  const int m0 = blockIdx.x * 128, n0 = blockIdx.y * 128;
  const unsigned short* Bz = Bt + blockIdx.z * BtStride;
  float* Cz = C + blockIdx.z * CStride;
  const int wm = (wave >> 1) * 64, wn = (wave & 1) * 64;

  f32x4 acc[4][4];
#pragma unroll
  for (int a = 0; a < 4; ++a)
#pragma unroll
    for (int bq = 0; bq < 4; ++bq) acc[a][bq] = (f32x4){0.f, 0.f, 0.f, 0.f};

  for (int k0 = 0; k0 < Kd; k0 += 32) {
#pragma unroll
    for (int it = 0; it < 2; ++it) {
      int cch = tid + 256 * it;
      int r = cch >> 2, cc = cch & 3;
      *(i32x4*)&Ash[r][cc * 8] = *(const i32x4*)(A + (size_t)(m0 + r) * Kd + k0 + cc * 8);
      *(i32x4*)&Bsh[r][cc * 8] = *(const i32x4*)(Bz + (size_t)(n0 + r) * Kd + k0 + cc * 8);
    }
    __syncthreads();
    short8 af[4], bfr[4];
#pragma unroll
    for (int mt = 0; mt < 4; ++mt) af[mt] = *(const short8*)&Ash[wm + mt * 16 + lr][g * 8];
#pragma unroll
    for (int nt = 0; nt < 4; ++nt) bfr[nt] = *(const short8*)&Bsh[wn + nt * 16 + lr][g * 8];
#pragma unroll
    for (int mt = 0; mt < 4; ++mt)
#pragma unroll
      for (int nt = 0; nt < 4; ++nt)
        acc[mt][nt] = __builtin_amdgcn_mfma_f32_16x16x32_bf16(af[mt], bfr[nt], acc[mt][nt], 0, 0, 0);
    __syncthreads();
  }
#pragma unroll
  for (int mt = 0; mt < 4; ++mt)
#pragma unroll
    for (int nt = 0; nt < 4; ++nt)
#pragma unroll
      for (int r = 0; r < 4; ++r) {
        int m = m0 + wm + mt * 16 + g * 4 + r;
        int n = n0 + wn + nt * 16 + lr;
        Cz[(size_t)m * Nd + n] = acc[mt][nt][r];
      }
}

// ---------------- split-bf16 (3-term f32-emulation) GEMM ----------------
// C = (Ah+Al)*(Bh+Bl)^T via AhBh + AhBl + AlBh; residual ~2^-18 relative.
__global__ __launch_bounds__(256) void gemm_split_kernel(
    const unsigned short* __restrict__ Ah, const unsigned short* __restrict__ Al,
    const unsigned short* __restrict__ Bth, const unsigned short* __restrict__ Btl,
    float* __restrict__ C, int Kd, int Nd, size_t BtStride, size_t CStride) {
  __shared__ unsigned short AshH[128][40];
  __shared__ unsigned short AshL[128][40];
  __shared__ unsigned short BshH[128][40];
  __shared__ unsigned short BshL[128][40];
  const int tid = threadIdx.x;
  const int wave = tid >> 6, lane = tid & 63;
  const int g = lane >> 4, lr = lane & 15;
  const int m0 = blockIdx.x * 128, n0 = blockIdx.y * 128;
  const unsigned short* Bzh = Bth + blockIdx.z * BtStride;
  const unsigned short* Bzl = Btl + blockIdx.z * BtStride;
  float* Cz = C + blockIdx.z * CStride;
  const int wm = (wave >> 1) * 64, wn = (wave & 1) * 64;

  f32x4 acc[4][4];
#pragma unroll
  for (int a = 0; a < 4; ++a)
#pragma unroll
    for (int bq = 0; bq < 4; ++bq) acc[a][bq] = (f32x4){0.f, 0.f, 0.f, 0.f};

  for (int k0 = 0; k0 < Kd; k0 += 32) {
#pragma unroll
    for (int it = 0; it < 2; ++it) {
      int cch = tid + 256 * it;
      int r = cch >> 2, cc = cch & 3;
      size_t ao = (size_t)(m0 + r) * Kd + k0 + cc * 8;
      size_t bo = (size_t)(n0 + r) * Kd + k0 + cc * 8;
      *(i32x4*)&AshH[r][cc * 8] = *(const i32x4*)(Ah + ao);
      *(i32x4*)&AshL[r][cc * 8] = *(const i32x4*)(Al + ao);
      *(i32x4*)&BshH[r][cc * 8] = *(const i32x4*)(Bzh + bo);
      *(i32x4*)&BshL[r][cc * 8] = *(const i32x4*)(Bzl + bo);
    }
    __syncthreads();
    short8 afh[4], afl[4], bfh[4], bfl[4];
#pragma unroll
    for (int mt = 0; mt < 4; ++mt) {
      afh[mt] = *(const short8*)&AshH[wm + mt * 16 + lr][g * 8];
      afl[mt] = *(const short8*)&AshL[wm + mt * 16 + lr][g * 8];
    }
#pragma unroll
    for (int nt = 0; nt < 4; ++nt) {
      bfh[nt] = *(const short8*)&BshH[wn + nt * 16 + lr][g * 8];
      bfl[nt] = *(const short8*)&BshL[wn + nt * 16 + lr][g * 8];
    }
#pragma unroll
    for (int mt = 0; mt < 4; ++mt)
#pragma unroll
      for (int nt = 0; nt < 4; ++nt) {
        f32x4 a = acc[mt][nt];
        a = __builtin_amdgcn_mfma_f32_16x16x32_bf16(afl[mt], bfh[nt], a, 0, 0, 0);
        a = __builtin_amdgcn_mfma_f32_16x16x32_bf16(afh[mt], bfl[nt], a, 0, 0, 0);
        a = __builtin_amdgcn_mfma_f32_16x16x32_bf16(afh[mt], bfh[nt], a, 0, 0, 0);
        acc[mt][nt] = a;
      }
    __syncthreads();
  }
#pragma unroll
  for (int mt = 0; mt < 4; ++mt)
#pragma unroll
    for (int nt = 0; nt < 4; ++nt)
#pragma unroll
      for (int r = 0; r < 4; ++r) {
        int m = m0 + wm + mt * 16 + g * 4 + r;
        int n = n0 + wn + nt * 16 + lr;
        Cz[(size_t)m * Nd + n] = acc[mt][nt][r];
      }
}

// ---------------- recurrent scan: 1 block (512 thr) per (b,n) chain ----------------
// Transposed: cand^T = W^T * H^T, W split hi/lo in regs, H split hi/lo in LDS.
// C-layout: lane holds cand[k = wk*16 + lr][w = (2wh+u)*16 + 4g + r].
// H planes bf16 row-major [k][v], XOR-swizzled: byte = k*128 + (2v ^ ((k&7)<<4)).
__global__ __launch_bounds__(512) void scan_kernel(
    const float* __restrict__ qbuf, const float* __restrict__ kbuf,
    const float* __restrict__ vbuf, const float* __restrict__ fbuf,
    const float* __restrict__ W, float* __restrict__ ybuf, float* __restrict__ Hout) {
  const int tid = threadIdx.x;
  const int wave = tid >> 6;
  const int lane = tid & 63;
  const int g = lane >> 4, lr = lane & 15;
  const int wk = wave & 3;    // k-row group
  const int wh = wave >> 2;   // w-half
  const int bz = blockIdx.x;
  const int b = bz >> 3, n = bz & 7;
  const int kq = wk * 16 + lr;
  const int swz = (kq & 7) << 4;

  __shared__ unsigned short Hh[64 * 64];   // hi plane, swizzled
  __shared__ unsigned short Hl[64 * 64];   // lo plane, swizzled
  __shared__ float stage[2][192];          // q[0:64) k[64:128) v[128:192)

  for (int i = tid; i < 2048; i += 512) ((unsigned int*)Hh)[i] = 0u;
  for (int i = tid; i < 2048; i += 512) ((unsigned int*)Hl)[i] = 0u;

  // A-frags: W^T split hi+lo bf16
  const float* Wn = W + (size_t)n * 4096;
  short8 Af[2][2], Alw[2][2];
#pragma unroll
  for (int u = 0; u < 2; ++u)
#pragma unroll
    for (int s = 0; s < 2; ++s) {
      int wcol = (wh * 2 + u) * 16 + lr;
      short8 ah, al;
#pragma unroll
      for (int j = 0; j < 8; ++j) {
        int v = s * 32 + g * 8 + j;
        float wv = Wn[(size_t)v * 64 + wcol];
        unsigned short hb = f2bf(wv);
        ah[j] = (short)hb;
        al[j] = (short)f2bf(wv - bf2f(hb));
      }
      Af[u][s] = ah; Alw[u][s] = al;
    }

  // q/k/v staging: threads 256..447 own one element each (double buffer)
  const float* psrc = nullptr;
  int pidx = tid - 256;
  if (pidx >= 0 && pidx < 192) {
    int which = pidx >> 6, e = pidx & 63;
    const float* base = (which == 0) ? qbuf : (which == 1) ? kbuf : vbuf;
    psrc = base + (size_t)b * 1024 * 512 + n * 64 + e;
    stage[0][pidx] = psrc[0];
  }
  const float* fbase = fbuf + (size_t)b * 1024 * 8 + n;
  float fcur = fbase[0];

  f32x4 Hreg[2];   // f32 master: Hreg[u][r] = H[kq][(2wh+u)*16 + 4g + r]
  Hreg[0] = (f32x4){0.f, 0.f, 0.f, 0.f};
  Hreg[1] = (f32x4){0.f, 0.f, 0.f, 0.f};

  __syncthreads();

  int p = 0;
  for (int t = 0; t < 1024; ++t) {
    // B-frags of H_t^T (hi and lo planes), conflict-free via swizzle
    const char* hrh = (const char*)(Hh + kq * 64);
    const char* hrl = (const char*)(Hl + kq * 64);
    short8 Bh0 = *(const short8*)(hrh + ((16 * g) ^ swz));
    short8 Bh1 = *(const short8*)(hrh + ((64 + 16 * g) ^ swz));
    short8 Bl0 = *(const short8*)(hrl + ((16 * g) ^ swz));
    short8 Bl1 = *(const short8*)(hrl + ((64 + 16 * g) ^ swz));

    f32x4 acc[2];
#pragma unroll
    for (int u = 0; u < 2; ++u) {
      f32x4 a = (f32x4){0.f, 0.f, 0.f, 0.f};
      a = __builtin_amdgcn_mfma_f32_16x16x32_bf16(Alw[u][0], Bl0, a, 0, 0, 0);
      a = __builtin_amdgcn_mfma_f32_16x16x32_bf16(Alw[u][1], Bl1, a, 0, 0, 0);
      a = __builtin_amdgcn_mfma_f32_16x16x32_bf16(Alw[u][0], Bh0, a, 0, 0, 0);
      a = __builtin_amdgcn_mfma_f32_16x16x32_bf16(Alw[u][1], Bh1, a, 0, 0, 0);
      a = __builtin_amdgcn_mfma_f32_16x16x32_bf16(Af[u][0], Bl0, a, 0, 0, 0);
      a = __builtin_amdgcn_mfma_f32_16x16x32_bf16(Af[u][1], Bl1, a, 0, 0, 0);
      a = __builtin_amdgcn_mfma_f32_16x16x32_bf16(Af[u][0], Bh0, a, 0, 0, 0);
      a = __builtin_amdgcn_mfma_f32_16x16x32_bf16(Af[u][1], Bh1, a, 0, 0, 0);
      acc[u] = a;
    }

    float kval = stage[p][64 + kq];
    f32x4 vv[2];
#pragma unroll
    for (int u = 0; u < 2; ++u)
      vv[u] = *(const f32x4*)&stage[p][128 + (wh * 2 + u) * 16 + g * 4];

    float pref = 0.f;
    if (psrc && t + 1 < 1024) pref = psrc[(size_t)(t + 1) * 512];
    float fnext = (t + 1 < 1024) ? fbase[(size_t)(t + 1) * 8] : 0.f;

    float gf = fcur, omg = 1.f - fcur;
#pragma unroll
    for (int u = 0; u < 2; ++u)
#pragma unroll
      for (int r = 0; r < 4; ++r) {
        float cand = tanhf_fast(acc[u][r] + kval * vv[u][r]);
        Hreg[u][r] = gf * Hreg[u][r] + omg * cand;
      }

    __syncthreads();  // B1: all H_t reads done

    {  // write H_{t+1} hi+lo bf16 (4 consecutive w -> one b64 each), swizzled
      char* hwh = (char*)(Hh + kq * 64);
      char* hwl = (char*)(Hl + kq * 64);
#pragma unroll
      for (int u = 0; u < 2; ++u) {
        unsigned short h0 = f2bf(Hreg[u][0]), h1 = f2bf(Hreg[u][1]);
        unsigned short h2 = f2bf(Hreg[u][2]), h3 = f2bf(Hreg[u][3]);
        unsigned short l0 = f2bf(Hreg[u][0] - bf2f(h0)), l1 = f2bf(Hreg[u][1] - bf2f(h1));
        unsigned short l2 = f2bf(Hreg[u][2] - bf2f(h2)), l3 = f2bf(Hreg[u][3] - bf2f(h3));
        u32x2 ph = {(unsigned)h0 | ((unsigned)h1 << 16), (unsigned)h2 | ((unsigned)h3 << 16)};
        u32x2 pl = {(unsigned)l0 | ((unsigned)l1 << 16), (unsigned)l2 | ((unsigned)l3 << 16)};
        int off = ((wh * 2 + u) * 32 + 8 * g) ^ swz;
        *(u32x2*)(hwh + off) = ph;
        *(u32x2*)(hwl + off) = pl;
      }
    }
    if (psrc && t + 1 < 1024) stage[1 - p][pidx] = pref;

    __syncthreads();  // B2: H planes = H_{t+1}, stage[1-p] ready

    // y_t[v] = sum_k q_t[k] * H_{t+1}[k][v]  (waves 0..3)
    if (wave < 4) {
      int vcol = wave * 16 + lr;
      float sum = 0.f;
#pragma unroll
      for (int kk2 = 0; kk2 < 16; ++kk2) {
        int kk = g * 16 + kk2;
        int boff = kk * 128 + ((2 * vcol) ^ ((kk & 7) << 4));
        float hv = bf2f(*(const unsigned short*)((const char*)Hh + boff)) +
                   bf2f(*(const unsigned short*)((const char*)Hl + boff));
        sum += stage[p][kk] * hv;
      }
      sum += __shfl_xor(sum, 16, 64);
      sum += __shfl_xor(sum, 32, 64);
      if (g == 0)
        ybuf[((size_t)(b * 1024 + t) * 8 + n) * 64 + vcol] = sum;
    }
    fcur = fnext;
    p ^= 1;
  }

  // H_final (f32 master)
  float* Ho = Hout + (size_t)(b * 8 + n) * 4096;
#pragma unroll
  for (int u = 0; u < 2; ++u)
    *(f32x4*)&Ho[(size_t)kq * 64 + (wh * 2 + u) * 16 + g * 4] = Hreg[u];
}

// ---------------- launch ----------------
extern "C" void kernel_launch(void* const* d_in, const int* in_sizes, int n_in,
                              void* d_out, int out_size, void* d_ws, size_t ws_size,
                              hipStream_t stream) {
  const float* x   = (const float*)d_in[0];
  const float* Wq  = (const float*)d_in[1];
  const float* Wk  = (const float*)d_in[2];
  const float* Wv  = (const float*)d_in[3];
  const float* Wf  = (const float*)d_in[4];
  const float* bfv = (const float*)d_in[5];
  const float* cwq = (const float*)d_in[6];
  const float* cwk = (const float*)d_in[7];
  const float* cwv = (const float*)d_in[8];
  const float* W   = (const float*)d_in[9];
  const float* Wo  = (const float*)d_in[10];
  float* outp = (float*)d_out;

  char* ws = (char*)d_ws;
  size_t off = 0;
  auto alloc = [&](size_t bytes) {
    char* pp = ws + off;
    off = (off + bytes + 255) & ~(size_t)255;
    return pp;
  };
  unsigned short* xbh  = (unsigned short*)alloc((size_t)4194304 * 2);
  unsigned short* xbl  = (unsigned short*)alloc((size_t)4194304 * 2);
  unsigned short* wtbh = (unsigned short*)alloc((size_t)3 * 524288 * 2);
  unsigned short* wtbl = (unsigned short*)alloc((size_t)3 * 524288 * 2);
  float* pre  = (float*)alloc((size_t)3 * 2097152 * 4);
  float* qkv  = (float*)alloc((size_t)3 * 2097152 * 4);
  float* fbuf = (float*)alloc((size_t)32768 * 4);
  float* ybuf = (float*)alloc((size_t)2097152 * 4);
  unsigned short* yb  = (unsigned short*)alloc((size_t)2097152 * 2);
  unsigned short* wot = (unsigned short*)alloc((size_t)524288 * 2);

  // casts / transposes (split hi/lo for the amplified path)
  cast_split_kernel<<<4096, 256, 0, stream>>>(x, xbh, xbl, 1048576);
  tcast_split_kernel<<<2048, 256, 0, stream>>>(Wq, wtbh, wtbl, 1024, 512);
  tcast_split_kernel<<<2048, 256, 0, stream>>>(Wk, wtbh + 524288, wtbl + 524288, 1024, 512);
  tcast_split_kernel<<<2048, 256, 0, stream>>>(Wv, wtbh + 2 * 524288, wtbl + 2 * 524288, 1024, 512);
  // gate
  fgate_kernel<<<1024, 256, 0, stream>>>(x, Wf, bfv, fbuf);
  // q/k/v pre-activations (split-bf16 f32-emulated GEMM)
  dim3 g1(32, 4, 3);
  gemm_split_kernel<<<g1, 256, 0, stream>>>(xbh, xbl, wtbh, wtbl, pre, 1024, 512,
                                            (size_t)524288, (size_t)2097152);
  // conv + silu
  conv_silu_kernel<<<8192, 256, 0, stream>>>(pre,               cwq, qkv);
  conv_silu_kernel<<<8192, 256, 0, stream>>>(pre + 2097152,     cwk, qkv + 2097152);
  conv_silu_kernel<<<8192, 256, 0, stream>>>(pre + 2 * 2097152, cwv, qkv + 2 * 2097152);
  // recurrent scan (writes ybuf and H_final tail of d_out)
  scan_kernel<<<32, 512, 0, stream>>>(qkv, qkv + 2097152, qkv + 2 * 2097152, fbuf, W,
                                      ybuf, outp + 4194304);
  // output projection (plain bf16: direct, un-amplified error ~0.006)
  cast_bf16_kernel<<<2048, 256, 0, stream>>>(ybuf, yb, 524288);
  tcast_kernel<<<2048, 256, 0, stream>>>(Wo, wot, 512, 1024);
  dim3 g2(32, 8, 1);
  gemm_bf16_kernel<<<g2, 256, 0, stream>>>(yb, wot, outp, 512, 1024, (size_t)0, (size_t)0);
}